// Round 10
// baseline (16041.518 us; speedup 1.0000x reference)
//
#include <hip/hip_runtime.h>
#include <stdint.h>

#define T_STEPS 4096
#define BATCH 32
#define HID 512
#define GROUPS 8            // blocks per batch
#define BLK_THREADS 1024    // 16 waves; 256 blocks = exactly 1/CU
#define NBLOCKS 256

typedef _Float16 h2_t __attribute__((ext_vector_type(2)));
typedef uint32_t u32x16 __attribute__((ext_vector_type(16)));

__device__ inline uint32_t pack_h2(float a, float b) {
  h2_t v;
  v.x = (_Float16)a;
  v.y = (_Float16)b;
  return __builtin_bit_cast(uint32_t, v);
}

__device__ inline float fdot2(uint32_t a, uint32_t b, float c) {
  return __builtin_amdgcn_fdot2(__builtin_bit_cast(h2_t, a),
                                __builtin_bit_cast(h2_t, b), c, false);
}

// AGPR-resident weight read (unified RF; proven rounds 3-9: FETCH_SIZE
// ~95 MB == one-time traffic only).
__device__ inline uint32_t aread(uint32_t a) {
  uint32_t v;
  asm("v_accvgpr_read_b32 %0, %1" : "=v"(v) : "a"(a));
  return v;
}

// Launder a wave-uniform pointer into SGPRs for "s" asm constraints.
__device__ inline uint64_t uni64(const void* p) {
  uint32_t lo = __builtin_amdgcn_readfirstlane((uint32_t)(uintptr_t)p);
  uint32_t hi = __builtin_amdgcn_readfirstlane((uint32_t)((uintptr_t)p >> 32));
  return ((uint64_t)hi << 32) | lo;
}

__device__ inline void kinv() {
  asm volatile("s_dcache_inv" ::: "memory");
}
// The round-10 fix: ALL FOUR x16 loads issued back-to-back, ONE waitcnt.
// Round 9's per-load embedded waitcnt serialized them into 3 L2 round
// trips per step (and the counter->data dependency added another).
__device__ inline void sload64(uint64_t p, u32x16& h0, u32x16& h1,
                               u32x16& h2, u32x16& h3) {
  asm volatile(
      "s_load_dwordx16 %0, %4, 0x0\n\t"
      "s_load_dwordx16 %1, %4, 0x40\n\t"
      "s_load_dwordx16 %2, %4, 0x80\n\t"
      "s_load_dwordx16 %3, %4, 0xc0\n\t"
      "s_waitcnt lgkmcnt(0)"
      : "=s"(h0), "=s"(h1), "=s"(h2), "=s"(h3)
      : "s"(p) : "memory");
}

__device__ inline float sigf(float x) { return 1.0f / (1.0f + __expf(-x)); }
__device__ inline float tanh_fast(float x) {
  float a = fabsf(x);
  float e = __expf(-2.0f * a);
  float r = (1.0f - e) / (1.0f + e);
  return copysignf(r, x);
}

// Round 10: XCD-claimed placement (XCD L2 = legal coherence point, rounds
// 6-9) + SELF-VALIDATING tagged h over the scalar path.
//
// Producer (wave 0, 64 lanes): h dword = (t+1)<<16 | f16(h). One 256B
// coalesced store. NO drain, NO counter — each dword self-validates, so
// there is nothing to order (word atomicity).
// Consumer (each wave): kinv -> 4x s_load_dwordx16 (one waitcnt, one L2
// round trip) of its 64-dword column slice -> SALU tag check (OR of XORs)
// -> retry w/ s_sleep if any tag != t -> SALU pair packing -> fdot2 w/ SGPR
// src. Polls spread over 16 distinct 256B slices per batch — kills the
// round-9 hot counter line (128 waves on one 64B line = L2 queue
// congestion = suspected metastable slow mode).
// Parity (2-slot) buffering: block publishes h_{t+2} over h_t only after
// its step-t+1 poll passed, which implies every block consumed h_t. Tag
// mismatch on any torn/stale read just retries — stale consumption is
// structurally impossible (falsifiable via absmax: must return to ~1e-2).
__global__ __launch_bounds__(BLK_THREADS)
void lstm_tag(const float* __restrict__ x0,
              const float* __restrict__ W_ih,
              const float* __restrict__ W_hh,
              const float* __restrict__ b_ih,
              const float* __restrict__ b_hh,
              const float* __restrict__ W_lin,
              const float* __restrict__ b_lin,
              float* __restrict__ y,
              uint32_t* __restrict__ h_ex,   // [2][BATCH][512] tagged f16
              int* __restrict__ claim)       // [8][16] per-XCD claim ctrs
{
  __shared__ float x0_lds[T_STEPS];     // 16 KB: this batch's x0 column
  __shared__ float ylds[T_STEPS];       // 16 KB: per-block y partials
  __shared__ float gacc[2][256];        // parity-buffered gate accumulators
  __shared__ int s_bg;

  const int tid = threadIdx.x;

  // ---- claim a (batch, group) slot on THIS block's physical XCD ----
  if (tid == 0) {
    uint32_t xcc;
    asm volatile("s_getreg_b32 %0, hwreg(HW_REG_XCC_ID)" : "=s"(xcc));
    xcc &= 7;
    int slot = atomicAdd(claim + xcc * 16, 1);   // agent-scope, one-time
    s_bg = (slot < 32) ? (int)(((4 * xcc + (slot >> 3)) << 3) | (slot & 7))
                       : -1;
  }
  __syncthreads();
  if (s_bg < 0) return;                  // surplus block
  const int b  = s_bg >> 3;              // batch (same XCD for all 8 groups)
  const int g  = s_bg & 7;               // group within batch
  const int u0 = g * 64;                 // first hidden unit owned
  const int wv = tid >> 6;               // wave 0..15
  const int rg = wv >> 3;                // row-group 0..1
  const int cs = wv & 7;                 // col-slice 0..7 == producer group
  const int l  = tid & 63;

  // ---- one-time: W_hh slice -> packed f16x2 -> AGPRs ----
  uint32_t a0[32], a1[32];
  {
    const int r0 = 128 * rg + l;
    const int r1 = r0 + 64;
    const int R0 = (r0 >> 6) * HID + u0 + (r0 & 63);  // gate*512 + unit
    const int R1 = (r1 >> 6) * HID + u0 + (r1 & 63);
    const float2* p0 = (const float2*)(W_hh + (size_t)R0 * HID + 64 * cs);
    const float2* p1 = (const float2*)(W_hh + (size_t)R1 * HID + 64 * cs);
#pragma unroll
    for (int k = 0; k < 32; ++k) {
      float2 a = p0[k], c = p1[k];
      uint32_t t0 = pack_h2(a.x, a.y);
      uint32_t t1 = pack_h2(c.x, c.y);
      asm("v_accvgpr_write_b32 %0, %1" : "=a"(a0[k]) : "v"(t0));
      asm("v_accvgpr_write_b32 %0, %1" : "=a"(a1[k]) : "v"(t1));
    }
  }
  // ---- one-time: x0 column, y partials, gacc ----
  for (int i = tid; i < T_STEPS; i += BLK_THREADS) {
    x0_lds[i] = x0[i * BATCH + b];
    ylds[i] = 0.f;
  }
  if (tid < 256) { gacc[0][tid] = 0.f; gacc[1][tid] = 0.f; }

  // ---- activation-lane constants (lanes 0..63 of wave 0) ----
  float c_state = 0.f;
  float wih_[4] = {0.f, 0.f, 0.f, 0.f}, bs_[4] = {0.f, 0.f, 0.f, 0.f};
  float wlin_u = 0.f, blin = 0.f;
  if (tid < 64) {
#pragma unroll
    for (int j = 0; j < 4; ++j) {
      int R = j * HID + u0 + tid;
      wih_[j] = W_ih[R];
      bs_[j] = b_ih[R] + b_hh[R];
    }
    wlin_u = W_lin[u0 + tid];
    blin = b_lin[0];
  }

  // ---- addresses: consumer slice (SGPR, both parities) + publish ptrs ----
  uint32_t* hb = h_ex + (size_t)b * 512;            // parity stride BATCH*512
  const uint64_t dpu[2] = { uni64(hb + 64 * cs),
                            uni64(hb + BATCH * 512 + 64 * cs) };
  uint32_t* pub01[2] = { hb + u0 + tid, hb + BATCH * 512 + u0 + tid };

  __syncthreads();

  int dead = 0;
  for (int t = 0; t < T_STEPS; ++t) {
    const int sl = t & 1, ns = sl ^ 1;

    // ---- poll own 64-dword tagged slice: one L2 round trip per try ----
    u32x16 h0, h1, h2, h3;
    {
      const uint32_t tw = (uint32_t)t << 16;
      int guard = 0;
      for (;;) {
        kinv();
        sload64(dpu[sl], h0, h1, h2, h3);
        uint32_t bad = 0;
#pragma unroll
        for (int k = 0; k < 16; ++k) {
          bad |= (h0[k] ^ tw) | (h1[k] ^ tw) | (h2[k] ^ tw) | (h3[k] ^ tw);
        }
        if ((bad & 0xffff0000u) == 0u) break;
        if (dead || ++guard > (1 << 20)) { dead = 1; break; }  // anti-hang
        __builtin_amdgcn_s_sleep(1);
      }
    }
    // ---- SALU pair packing: (h_{2e+1}<<16)|h_{2e} ----
    uint32_t pk[32];
#pragma unroll
    for (int e = 0; e < 8; ++e) {
      pk[e]      = (h0[2 * e] & 0xffffu) | (h0[2 * e + 1] << 16);
      pk[8 + e]  = (h1[2 * e] & 0xffffu) | (h1[2 * e + 1] << 16);
      pk[16 + e] = (h2[2 * e] & 0xffffu) | (h2[2 * e + 1] << 16);
      pk[24 + e] = (h3[2 * e] & 0xffffu) | (h3[2 * e + 1] << 16);
    }
    // ---- matvec: 2 rows x 64 cols per lane; h uniform from SGPRs ----
    float acc0 = 0.f, acc1 = 0.f;
#pragma unroll
    for (int k = 0; k < 32; ++k) {
      acc0 = fdot2(aread(a0[k]), pk[k], acc0);
      acc1 = fdot2(aread(a1[k]), pk[k], acc1);
    }
    atomicAdd(&gacc[sl][128 * rg + l], acc0);       // 2-way bank, conflict-free
    atomicAdd(&gacc[sl][128 * rg + 64 + l], acc1);
    __syncthreads();   // the ONE block barrier per step

    // ---- activations + publish (wave 0, 64 lanes = 64 owned units) ----
    if (tid < 64) {
      const float xv = x0_lds[t];
      float gi = gacc[sl][tid]       + xv * wih_[0] + bs_[0];
      float gf = gacc[sl][tid + 64]  + xv * wih_[1] + bs_[1];
      float gg = gacc[sl][tid + 128] + xv * wih_[2] + bs_[2];
      float go = gacc[sl][tid + 192] + xv * wih_[3] + bs_[3];
      float si = sigf(gi), sf = sigf(gf), tg_ = tanh_fast(gg), so = sigf(go);
      c_state = sf * c_state + si * tg_;
      float h = so * tanh_fast(c_state);

      // publish: tagged dword, one 256B coalesced store; self-validating,
      // so no drain and no counter
      uint16_t hbb = __builtin_bit_cast(uint16_t, (_Float16)h);
      pub01[ns][0] = ((uint32_t)(t + 1) << 16) | (uint32_t)hbb;

      // recycle gacc[sl] for step t+2 (safe: program order + next barrier)
      gacc[sl][tid] = 0.f;
      gacc[sl][tid + 64] = 0.f;
      gacc[sl][tid + 128] = 0.f;
      gacc[sl][tid + 192] = 0.f;

      // y partial (off critical path): fold 64 units -> ylds[t]
      float p = wlin_u * h;
#pragma unroll
      for (int m = 32; m >= 1; m >>= 1) p += __shfl_xor(p, m, 64);
      if (tid == 0) ylds[t] = p;
    }
  }

  // ---- drain: block partials -> global y (g==0 adds bias + residual) ----
  __syncthreads();
  for (int i = tid; i < T_STEPS; i += BLK_THREADS) {
    float val = ylds[i];
    if (g == 0) val += blin + x0_lds[i];
    unsafeAtomicAdd(&y[i * BATCH + b], val);
  }
}

extern "C" void kernel_launch(void* const* d_in, const int* in_sizes, int n_in,
                              void* d_out, int out_size, void* d_ws, size_t ws_size,
                              hipStream_t stream) {
  const float* x0    = (const float*)d_in[0];
  const float* W_ih  = (const float*)d_in[1];
  const float* W_hh  = (const float*)d_in[2];
  const float* b_ih  = (const float*)d_in[3];
  const float* b_hh  = (const float*)d_in[4];
  const float* W_lin = (const float*)d_in[5];
  const float* b_lin = (const float*)d_in[6];
  float* y = (float*)d_out;

  uint32_t* h_ex = (uint32_t*)d_ws;                     // [2][32][512] 128 KB
  int* claim = (int*)(h_ex + 2 * BATCH * 512);          // 512 B
  const size_t init_bytes =
      (size_t)2 * BATCH * 512 * sizeof(uint32_t) + 8 * 16 * sizeof(int);

  // memset 0: slot-0 tags = 0 with h = 0.0f16 == the h0 state; claim = 0
  (void)hipMemsetAsync(d_ws, 0, init_bytes, stream);
  (void)hipMemsetAsync(d_out, 0, (size_t)out_size * sizeof(float), stream);

  hipLaunchKernelGGL(lstm_tag, dim3(NBLOCKS), dim3(BLK_THREADS), 0, stream,
                     x0, W_ih, W_hh, b_ih, b_hh, W_lin, b_lin, y, h_ex, claim);
}

// Round 11
// 15982.515 us; speedup vs baseline: 1.0037x; 1.0037x over previous
//
#include <hip/hip_runtime.h>
#include <stdint.h>

#define T_STEPS 4096
#define BATCH 32
#define HID 512
#define GROUPS 8            // blocks per batch
#define BLK_THREADS 1024    // 16 waves
#define NBLOCKS 256
// Dynamic LDS pad: static (~35 KB) + 56 KB > 80 KB = 160/2, so the HW can
// host only ONE block per CU -> 256 blocks occupy exactly the 256 CUs ->
// each XCD hosts exactly 32 blocks -> the claim table fills exactly.
// This kills (a) orphan (b,g) slots (consumers guard-exhausted ~50 ms and
// free-ran on stale h => the 47-57 ms dispatches AND absmax 0.0469) and
// (b) double-stacked CUs convoying their batches at half speed.
#define DYN_LDS_PAD 57344

typedef _Float16 h2_t __attribute__((ext_vector_type(2)));
typedef uint32_t u32x16 __attribute__((ext_vector_type(16)));

__device__ inline uint32_t pack_h2(float a, float b) {
  h2_t v;
  v.x = (_Float16)a;
  v.y = (_Float16)b;
  return __builtin_bit_cast(uint32_t, v);
}

__device__ inline float fdot2(uint32_t a, uint32_t b, float c) {
  return __builtin_amdgcn_fdot2(__builtin_bit_cast(h2_t, a),
                                __builtin_bit_cast(h2_t, b), c, false);
}

// AGPR-resident weight read (unified RF; proven rounds 3-10: FETCH_SIZE
// ~95 MB == one-time traffic only).
__device__ inline uint32_t aread(uint32_t a) {
  uint32_t v;
  asm("v_accvgpr_read_b32 %0, %1" : "=v"(v) : "a"(a));
  return v;
}

// Launder a wave-uniform pointer into SGPRs for "s" asm constraints.
__device__ inline uint64_t uni64(const void* p) {
  uint32_t lo = __builtin_amdgcn_readfirstlane((uint32_t)(uintptr_t)p);
  uint32_t hi = __builtin_amdgcn_readfirstlane((uint32_t)((uintptr_t)p >> 32));
  return ((uint64_t)hi << 32) | lo;
}

__device__ inline void kinv() {
  asm volatile("s_dcache_inv" ::: "memory");
}
// All four x16 loads back-to-back, ONE waitcnt = one L2 round trip.
__device__ inline void sload64(uint64_t p, u32x16& h0, u32x16& h1,
                               u32x16& h2, u32x16& h3) {
  asm volatile(
      "s_load_dwordx16 %0, %4, 0x0\n\t"
      "s_load_dwordx16 %1, %4, 0x40\n\t"
      "s_load_dwordx16 %2, %4, 0x80\n\t"
      "s_load_dwordx16 %3, %4, 0xc0\n\t"
      "s_waitcnt lgkmcnt(0)"
      : "=s"(h0), "=s"(h1), "=s"(h2), "=s"(h3)
      : "s"(p) : "memory");
}

__device__ inline float sigf(float x) { return 1.0f / (1.0f + __expf(-x)); }
__device__ inline float tanh_fast(float x) {
  float a = fabsf(x);
  float e = __expf(-2.0f * a);
  float r = (1.0f - e) / (1.0f + e);
  return copysignf(r, x);
}

// Round 11 = round 10 (XCD-claimed placement + self-validating tagged h
// over the scalar path) + GUARANTEED 1-block/CU placement via >80 KB LDS.
// Sync recap: producer wave stores 64 tagged dwords ((t+1)<<16 | f16(h)),
// one 256B coalesced store, no drain/counter (word-atomic self-validation).
// Consumer wave: kinv -> 4x s_load_dwordx16 (one waitcnt) -> SALU tag check
// -> retry with s_sleep -> SALU pair pack -> fdot2 with SGPR-uniform h.
__global__ __launch_bounds__(BLK_THREADS)
void lstm_tag(const float* __restrict__ x0,
              const float* __restrict__ W_ih,
              const float* __restrict__ W_hh,
              const float* __restrict__ b_ih,
              const float* __restrict__ b_hh,
              const float* __restrict__ W_lin,
              const float* __restrict__ b_lin,
              float* __restrict__ y,
              uint32_t* __restrict__ h_ex,   // [2][BATCH][512] tagged f16
              int* __restrict__ claim)       // [8][16] per-XCD claim ctrs
{
  extern __shared__ char dynpad[];      // 56 KB occupancy pad (never touched)
  __shared__ float x0_lds[T_STEPS];     // 16 KB: this batch's x0 column
  __shared__ float ylds[T_STEPS];       // 16 KB: per-block y partials
  __shared__ float gacc[2][256];        // parity-buffered gate accumulators
  __shared__ int s_bg;

  const int tid = threadIdx.x;

  // ---- claim a (batch, group) slot on THIS block's physical XCD ----
  if (tid == 0) {
    uint32_t xcc;
    asm volatile("s_getreg_b32 %0, hwreg(HW_REG_XCC_ID)" : "=s"(xcc));
    xcc &= 7;
    int slot = atomicAdd(claim + xcc * 16, 1);   // agent-scope, one-time
    s_bg = (slot < 32) ? (int)(((4 * xcc + (slot >> 3)) << 3) | (slot & 7))
                       : -1;
    if (s_bg == -2) dynpad[0] = 1;      // keep the pad allocated
  }
  __syncthreads();
  if (s_bg < 0) return;                  // cannot happen with 1 blk/CU
  const int b  = s_bg >> 3;              // batch (same XCD for all 8 groups)
  const int g  = s_bg & 7;               // group within batch
  const int u0 = g * 64;                 // first hidden unit owned
  const int wv = tid >> 6;               // wave 0..15
  const int rg = wv >> 3;                // row-group 0..1
  const int cs = wv & 7;                 // col-slice 0..7 == producer group
  const int l  = tid & 63;

  // ---- one-time: W_hh slice -> packed f16x2 -> AGPRs ----
  uint32_t a0[32], a1[32];
  {
    const int r0 = 128 * rg + l;
    const int r1 = r0 + 64;
    const int R0 = (r0 >> 6) * HID + u0 + (r0 & 63);  // gate*512 + unit
    const int R1 = (r1 >> 6) * HID + u0 + (r1 & 63);
    const float2* p0 = (const float2*)(W_hh + (size_t)R0 * HID + 64 * cs);
    const float2* p1 = (const float2*)(W_hh + (size_t)R1 * HID + 64 * cs);
#pragma unroll
    for (int k = 0; k < 32; ++k) {
      float2 a = p0[k], c = p1[k];
      uint32_t t0 = pack_h2(a.x, a.y);
      uint32_t t1 = pack_h2(c.x, c.y);
      asm("v_accvgpr_write_b32 %0, %1" : "=a"(a0[k]) : "v"(t0));
      asm("v_accvgpr_write_b32 %0, %1" : "=a"(a1[k]) : "v"(t1));
    }
  }
  // ---- one-time: x0 column, y partials, gacc ----
  for (int i = tid; i < T_STEPS; i += BLK_THREADS) {
    x0_lds[i] = x0[i * BATCH + b];
    ylds[i] = 0.f;
  }
  if (tid < 256) { gacc[0][tid] = 0.f; gacc[1][tid] = 0.f; }

  // ---- activation-lane constants (lanes 0..63 of wave 0) ----
  float c_state = 0.f;
  float wih_[4] = {0.f, 0.f, 0.f, 0.f}, bs_[4] = {0.f, 0.f, 0.f, 0.f};
  float wlin_u = 0.f, blin = 0.f;
  if (tid < 64) {
#pragma unroll
    for (int j = 0; j < 4; ++j) {
      int R = j * HID + u0 + tid;
      wih_[j] = W_ih[R];
      bs_[j] = b_ih[R] + b_hh[R];
    }
    wlin_u = W_lin[u0 + tid];
    blin = b_lin[0];
  }

  // ---- addresses: consumer slice (SGPR, both parities) + publish ptrs ----
  uint32_t* hb = h_ex + (size_t)b * 512;            // parity stride BATCH*512
  const uint64_t dpu[2] = { uni64(hb + 64 * cs),
                            uni64(hb + BATCH * 512 + 64 * cs) };
  uint32_t* pub01[2] = { hb + u0 + tid, hb + BATCH * 512 + u0 + tid };

  __syncthreads();

  int dead = 0;
  for (int t = 0; t < T_STEPS; ++t) {
    const int sl = t & 1, ns = sl ^ 1;

    // ---- poll own 64-dword tagged slice: one L2 round trip per try ----
    u32x16 h0, h1, h2, h3;
    {
      const uint32_t tw = (uint32_t)t << 16;
      int guard = 0;
      for (;;) {
        kinv();
        sload64(dpu[sl], h0, h1, h2, h3);
        uint32_t bad = 0;
#pragma unroll
        for (int k = 0; k < 16; ++k) {
          bad |= (h0[k] ^ tw) | (h1[k] ^ tw) | (h2[k] ^ tw) | (h3[k] ^ tw);
        }
        if ((bad & 0xffff0000u) == 0u) break;
        if (dead || ++guard > (1 << 20)) { dead = 1; break; }  // anti-hang
        __builtin_amdgcn_s_sleep(1);
      }
    }
    // ---- SALU pair packing: (h_{2e+1}<<16)|h_{2e} ----
    uint32_t pk[32];
#pragma unroll
    for (int e = 0; e < 8; ++e) {
      pk[e]      = (h0[2 * e] & 0xffffu) | (h0[2 * e + 1] << 16);
      pk[8 + e]  = (h1[2 * e] & 0xffffu) | (h1[2 * e + 1] << 16);
      pk[16 + e] = (h2[2 * e] & 0xffffu) | (h2[2 * e + 1] << 16);
      pk[24 + e] = (h3[2 * e] & 0xffffu) | (h3[2 * e + 1] << 16);
    }
    // ---- matvec: 2 rows x 64 cols per lane; h uniform from SGPRs ----
    float acc0 = 0.f, acc1 = 0.f;
#pragma unroll
    for (int k = 0; k < 32; ++k) {
      acc0 = fdot2(aread(a0[k]), pk[k], acc0);
      acc1 = fdot2(aread(a1[k]), pk[k], acc1);
    }
    atomicAdd(&gacc[sl][128 * rg + l], acc0);       // 2-way bank, conflict-free
    atomicAdd(&gacc[sl][128 * rg + 64 + l], acc1);
    __syncthreads();   // the ONE block barrier per step

    // ---- activations + publish (wave 0, 64 lanes = 64 owned units) ----
    if (tid < 64) {
      const float xv = x0_lds[t];
      float gi = gacc[sl][tid]       + xv * wih_[0] + bs_[0];
      float gf = gacc[sl][tid + 64]  + xv * wih_[1] + bs_[1];
      float gg = gacc[sl][tid + 128] + xv * wih_[2] + bs_[2];
      float go = gacc[sl][tid + 192] + xv * wih_[3] + bs_[3];
      float si = sigf(gi), sf = sigf(gf), tg_ = tanh_fast(gg), so = sigf(go);
      c_state = sf * c_state + si * tg_;
      float h = so * tanh_fast(c_state);

      // publish: tagged dword, one 256B coalesced store; self-validating
      uint16_t hbb = __builtin_bit_cast(uint16_t, (_Float16)h);
      pub01[ns][0] = ((uint32_t)(t + 1) << 16) | (uint32_t)hbb;

      // recycle gacc[sl] for step t+2 (safe: program order + next barrier)
      gacc[sl][tid] = 0.f;
      gacc[sl][tid + 64] = 0.f;
      gacc[sl][tid + 128] = 0.f;
      gacc[sl][tid + 192] = 0.f;

      // y partial (off critical path): fold 64 units -> ylds[t]
      float p = wlin_u * h;
#pragma unroll
      for (int m = 32; m >= 1; m >>= 1) p += __shfl_xor(p, m, 64);
      if (tid == 0) ylds[t] = p;
    }
  }

  // ---- drain: block partials -> global y (g==0 adds bias + residual) ----
  __syncthreads();
  for (int i = tid; i < T_STEPS; i += BLK_THREADS) {
    float val = ylds[i];
    if (g == 0) val += blin + x0_lds[i];
    unsafeAtomicAdd(&y[i * BATCH + b], val);
  }
}

extern "C" void kernel_launch(void* const* d_in, const int* in_sizes, int n_in,
                              void* d_out, int out_size, void* d_ws, size_t ws_size,
                              hipStream_t stream) {
  const float* x0    = (const float*)d_in[0];
  const float* W_ih  = (const float*)d_in[1];
  const float* W_hh  = (const float*)d_in[2];
  const float* b_ih  = (const float*)d_in[3];
  const float* b_hh  = (const float*)d_in[4];
  const float* W_lin = (const float*)d_in[5];
  const float* b_lin = (const float*)d_in[6];
  float* y = (float*)d_out;

  uint32_t* h_ex = (uint32_t*)d_ws;                     // [2][32][512] 128 KB
  int* claim = (int*)(h_ex + 2 * BATCH * 512);          // 512 B
  const size_t init_bytes =
      (size_t)2 * BATCH * 512 * sizeof(uint32_t) + 8 * 16 * sizeof(int);

  // memset 0: slot-0 tags = 0 with h = 0.0f16 == the h0 state; claim = 0
  (void)hipMemsetAsync(d_ws, 0, init_bytes, stream);
  (void)hipMemsetAsync(d_out, 0, (size_t)out_size * sizeof(float), stream);

  hipLaunchKernelGGL(lstm_tag, dim3(NBLOCKS), dim3(BLK_THREADS),
                     DYN_LDS_PAD, stream,
                     x0, W_ih, W_hh, b_ih, b_hh, W_lin, b_lin, y, h_ex, claim);
}